// Round 1
// baseline (1036.524 us; speedup 1.0000x reference)
//
#include <hip/hip_runtime.h>
#include <math.h>

#define T_NO   200
#define C_NO   63
#define E_NO   2000
#define I_NO   500
#define TD     50000
#define TPAD   50048
#define EPSF   1e-8f

// workspace layout (float offsets)
#define WS_HE    0            // 63*200 = 12600
#define WS_HI    12600        // 63*200
#define WS_HOBS  25200        // 63*401 = 25263 (end 50463)
#define WS_SYNE  50464        // 64*50048 = 3203072
#define WS_SYNI  3253536      // 64*50048
#define WS_L0T   6456608      // 63*50048 = 3153024 (end 9609632 floats = 38.4 MB)

// ---------------- K1: filter banks (matches numpy float64 basis build) ----------
__global__ void filters_kernel(const float* __restrict__ Wsyn,   // (63,13,2)
                               const float* __restrict__ Wobs,   // (63,25)
                               float* __restrict__ ws) {
    const double PI = 3.14159265358979323846;
    int idx = blockIdx.x * blockDim.x + threadIdx.x;
    int stride = gridDim.x * blockDim.x;

    // h_e / h_i : 63 x 200
    for (int p = idx; p < 63 * 200; p += stride) {
        int c = p / 200, d = p - c * 200;
        double raw = 5.0 * log((double)d + 1.0 + 1e-8);
        float ae = 0.f, ai = 0.f;
        for (int b = 0; b < 13; ++b) {
            double phi = 0.5 * PI * (double)b;
            float bv = 0.f;
            if (raw >= phi - PI && raw <= phi + PI)
                bv = (float)(0.5 * cos(raw - phi) + 0.5);
            ae += Wsyn[(c * 13 + b) * 2 + 0] * bv;
            ai += Wsyn[(c * 13 + b) * 2 + 1] * bv;
        }
        ws[WS_HE + p] = ae;
        ws[WS_HI + p] = ai;
    }

    // h_obs : 63 x 401  (obs_basis row packing: i==0 full; 2i-1 covers d>=200; 2i covers d<=200)
    for (int p = idx; p < 63 * 401; p += stride) {
        int c = p / 401, d = p - c * 401;
        double raw = 5.0 * log(fabs((double)(d - 200)) + 1.0 + 1e-8);
        float acc = 0.f;
        for (int i = 0; i < 13; ++i) {
            double phi = 0.5 * PI * (double)i;
            float bv = 0.f;
            if (raw >= phi - PI && raw <= phi + PI)
                bv = (float)(0.5 * cos(raw - phi) + 0.5);
            float w;
            if (i == 0) {
                w = Wobs[c * 25];
            } else {
                w = 0.f;
                if (d >= 200) w += Wobs[c * 25 + 2 * i - 1];
                if (d <= 200) w += Wobs[c * 25 + 2 * i];
            }
            acc += w * bv;
        }
        ws[WS_HOBS + p] = acc;
    }
}

// ---------------- K2: skinny GEMM  synT[c][t] = sum_k S[t,k] * Cs[c+1,k] ------
// 64 t-rows x 64 c-cols per block (c=63 is a padding column), BK=32.
__global__ __launch_bounds__(256) void gemm_kernel(const float* __restrict__ S,
                                                   const float* __restrict__ Cs,
                                                   float* __restrict__ synT,
                                                   int K) {
    __shared__ float As[32 * 68];   // As[kk][r], stride 68 keeps 16B align, breaks conflicts
    __shared__ float Bs[32 * 68];   // Bs[kk][c]
    const int tid = threadIdx.x;
    const int ty = tid >> 4, tx = tid & 15;
    const int t0 = blockIdx.x * 64;

    float acc[4][4] = {};
    const int nk = (K + 31) / 32;
    for (int kc = 0; kc < nk; ++kc) {
        const int k0 = kc * 32;
        for (int l = tid; l < 512; l += 256) {
            int r = l >> 3;
            int kg = (l & 7) << 2;
            int k = k0 + kg;
            int t = t0 + r;
            float4 v = {0.f, 0.f, 0.f, 0.f};
            if (t < TD && k < K) v = *(const float4*)(S + (size_t)t * K + k);
            As[(kg + 0) * 68 + r] = v.x;
            As[(kg + 1) * 68 + r] = v.y;
            As[(kg + 2) * 68 + r] = v.z;
            As[(kg + 3) * 68 + r] = v.w;
            float4 w = {0.f, 0.f, 0.f, 0.f};
            if (r < 63 && k < K) w = *(const float4*)(Cs + (size_t)(r + 1) * K + k);
            Bs[(kg + 0) * 68 + r] = w.x;
            Bs[(kg + 1) * 68 + r] = w.y;
            Bs[(kg + 2) * 68 + r] = w.z;
            Bs[(kg + 3) * 68 + r] = w.w;
        }
        __syncthreads();
        #pragma unroll
        for (int kk = 0; kk < 32; ++kk) {
            const float4 a = *(const float4*)&As[kk * 68 + 4 * ty];
            const float4 b = *(const float4*)&Bs[kk * 68 + 4 * tx];
            float av[4] = {a.x, a.y, a.z, a.w};
            float bv[4] = {b.x, b.y, b.z, b.w};
            #pragma unroll
            for (int i = 0; i < 4; ++i)
                #pragma unroll
                for (int j = 0; j < 4; ++j)
                    acc[i][j] += av[i] * bv[j];
        }
        __syncthreads();
    }
    #pragma unroll
    for (int j = 0; j < 4; ++j) {
        int c = 4 * tx + j;
        float4 v = {acc[0][j], acc[1][j], acc[2][j], acc[3][j]};
        *(float4*)(synT + (size_t)c * TPAD + t0 + 4 * ty) = v;   // pad rows/cols OK
    }
}

// ---------------- K3: causal e/i FIR (200 taps) + acausal obs FIR (401 taps) --
// block: 128 threads, 512 t's (4 per thread), one channel c = blockIdx.y.
__global__ __launch_bounds__(128) void fir_kernel(const float* __restrict__ synE,
                                                  const float* __restrict__ synI,
                                                  const float* __restrict__ Z,
                                                  const float* __restrict__ he,
                                                  const float* __restrict__ hi,
                                                  const float* __restrict__ ho,
                                                  const float* __restrict__ Theta,
                                                  float* __restrict__ L0T) {
    __shared__ float ssm2[711 * 2];  // interleaved (e,i), t window [t0-199, t0+511]
    __shared__ float h2[200 * 2];    // interleaved (he,hi)
    __shared__ float zsm[912];       // z window [t0-200, t0+711]
    __shared__ float hos[401];

    const int c = blockIdx.y;
    const int t0 = blockIdx.x * 512;
    const int tid = threadIdx.x;

    for (int j = tid; j < 711; j += 128) {
        int t = t0 - 199 + j;
        bool ok = (t >= 0 && t < TD);
        ssm2[2 * j]     = ok ? synE[(size_t)c * TPAD + t] : 0.f;
        ssm2[2 * j + 1] = ok ? synI[(size_t)c * TPAD + t] : 0.f;
    }
    for (int j = tid; j < 912; j += 128) {
        int t = t0 - 200 + j;
        zsm[j] = (t >= 0 && t < TD) ? Z[t] : 0.f;
    }
    for (int d = tid; d < 200; d += 128) {
        h2[2 * d]     = he[c * 200 + d];
        h2[2 * d + 1] = hi[c * 200 + d];
    }
    for (int d = tid; d < 401; d += 128) hos[d] = ho[c * 401 + d];
    __syncthreads();

    const float th = Theta[c];
    float acc[4] = {th, th, th, th};

    #pragma unroll 2
    for (int d = 0; d < 200; ++d) {
        float hx = h2[2 * d], hy = h2[2 * d + 1];
        #pragma unroll
        for (int r = 0; r < 4; ++r) {
            int j = tid + 128 * r + 199 - d;
            acc[r] += ssm2[2 * j] * hx + ssm2[2 * j + 1] * hy;
        }
    }
    #pragma unroll 2
    for (int d = 0; d < 401; ++d) {
        float hv = hos[d];
        #pragma unroll
        for (int r = 0; r < 4; ++r)
            acc[r] += zsm[tid + 128 * r + 400 - d] * hv;
    }

    #pragma unroll
    for (int r = 0; r < 4; ++r) {
        int t = t0 + tid + 128 * r;
        if (t < TD) L0T[(size_t)c * TPAD + t] = acc[r];
    }
}

// ---------------- K4: transpose [c][t] -> [t][c] + Gumbel softmax + sigmoid ---
__global__ __launch_bounds__(256) void out_kernel(const float* __restrict__ L0T,
                                                  const float* __restrict__ u,
                                                  const float* __restrict__ temp_p,
                                                  float* __restrict__ out) {
    __shared__ float tile[63 * 65];
    const int t0 = blockIdx.x * 64;
    const int tid = threadIdx.x;

    for (int l = tid; l < 1008; l += 256) {       // 63 rows x 16 float4
        int cc = l >> 4;
        int jg = (l & 15) << 2;
        float4 v = *(const float4*)(L0T + (size_t)cc * TPAD + t0 + jg);
        tile[cc * 65 + jg + 0] = v.x;
        tile[cc * 65 + jg + 1] = v.y;
        tile[cc * 65 + jg + 2] = v.z;
        tile[cc * 65 + jg + 3] = v.w;
    }
    __syncthreads();

    const float inv_temp = 1.f / (*temp_p);
    for (int l = tid; l < 4032; l += 256) {
        int tl = l / 63;
        int cc = l - tl * 63;
        int t = t0 + tl;
        if (t < TD) {
            float L0 = tile[cc * 65 + tl];
            float2 uv = *(const float2*)(u + 2 * ((size_t)t * 63 + cc));
            float g0 = -logf(-logf(uv.x + EPSF) + EPSF);
            float g1 = -logf(-logf(uv.y + EPSF) + EPSF);
            float zh = 1.f / (1.f + expf(-((L0 + g0 - g1) * inv_temp)));
            float sg = 1.f / (1.f + expf(-L0));
            out[(size_t)t * 63 + cc] = zh;
            out[3150000 + (size_t)t * 63 + cc] = sg;
        }
    }
}

extern "C" void kernel_launch(void* const* d_in, const int* in_sizes, int n_in,
                              void* d_out, int out_size, void* d_ws, size_t ws_size,
                              hipStream_t stream) {
    (void)in_sizes; (void)n_in; (void)out_size; (void)ws_size;
    const float* S_e   = (const float*)d_in[0];
    const float* S_i   = (const float*)d_in[1];
    const float* Z     = (const float*)d_in[2];
    const float* temp  = (const float*)d_in[3];
    const float* u     = (const float*)d_in[4];
    const float* Ce    = (const float*)d_in[5];
    const float* Ci    = (const float*)d_in[6];
    const float* Wsyn  = (const float*)d_in[7];
    const float* Wobs  = (const float*)d_in[8];
    const float* Theta = (const float*)d_in[9];
    float* out = (float*)d_out;
    float* ws  = (float*)d_ws;

    float* he   = ws + WS_HE;
    float* hi   = ws + WS_HI;
    float* ho   = ws + WS_HOBS;
    float* synE = ws + WS_SYNE;
    float* synI = ws + WS_SYNI;
    float* L0T  = ws + WS_L0T;

    hipLaunchKernelGGL(filters_kernel, dim3(50), dim3(256), 0, stream, Wsyn, Wobs, ws);
    hipLaunchKernelGGL(gemm_kernel, dim3(782), dim3(256), 0, stream, S_e, Ce, synE, E_NO);
    hipLaunchKernelGGL(gemm_kernel, dim3(782), dim3(256), 0, stream, S_i, Ci, synI, I_NO);
    hipLaunchKernelGGL(fir_kernel, dim3(98, 63), dim3(128), 0, stream,
                       synE, synI, Z, he, hi, ho, Theta, L0T);
    hipLaunchKernelGGL(out_kernel, dim3(782), dim3(256), 0, stream, L0T, u, temp, out);
}